// Round 2
// baseline (60.262 us; speedup 1.0000x reference)
//
#include <hip/hip_runtime.h>

#define NIN   784
#define NOUT  512
#define NROWS 785      // NIN + 1 (bias row)
#define BATCH 256
#define CHUNK 99       // ceil(785/8)

static constexpr float G_MIN_F  = (float)(1.0 / 983.3);
static constexpr float G_DIFF_F = (float)(1.0 / 281.3 - 1.0 / 983.3);

// device fast transcendental: v_log_f32 (log2), v_exp_f32 (2^x)
__device__ __forceinline__ float dlog2(float v) { return __builtin_amdgcn_logf(v); }
__device__ __forceinline__ float dexp2(float v) { return __builtin_amdgcn_exp2f(v); }

// ---------------------------------------------------------------------------
// Kernel 1: global max(|weights|) over w_pos, w_neg, b_pos, b_neg.
// All values are >= 0 after fabsf, so uint bit-pattern ordering == float order.
// ---------------------------------------------------------------------------
__global__ __launch_bounds__(256) void mk_max(
    const float* __restrict__ wp, const float* __restrict__ wn,
    const float* __restrict__ bp, const float* __restrict__ bn,
    unsigned int* __restrict__ out)
{
    float m = 0.0f;
    const int n = NIN * NOUT;
    for (int idx = blockIdx.x * 256 + threadIdx.x; idx < n; idx += gridDim.x * 256) {
        m = fmaxf(m, fabsf(wp[idx]));
        m = fmaxf(m, fabsf(wn[idx]));
    }
    if (blockIdx.x == 0 && threadIdx.x < NOUT) {
        m = fmaxf(m, fabsf(bp[threadIdx.x]));
        m = fmaxf(m, fabsf(bn[threadIdx.x]));
    }
    #pragma unroll
    for (int off = 1; off < 64; off <<= 1)
        m = fmaxf(m, __shfl_xor(m, off, 64));
    __shared__ float sm[4];
    if ((threadIdx.x & 63) == 0) sm[threadIdx.x >> 6] = m;
    __syncthreads();
    if (threadIdx.x == 0) {
        m = fmaxf(fmaxf(sm[0], sm[1]), fmaxf(sm[2], sm[3]));
        atomicMax(out, __float_as_uint(m));
    }
}

// ---------------------------------------------------------------------------
// Kernel 2: main memristor crossbar.
// y[b,j] = C * sum_i s[b,i] * ( 2^(ep*L + lgGp) - 2^(en*L + lgGn) )
//   L = log2(2|x[b,i]|), ep/en = log2(n_param[i, 2j/2j+1]),
//   lgG = log2(G_MIN + kG*max(w,0)),  C = V_REF/(k_V*k_G) = 0.5/kG
// Grid: (8 col-tiles of 64 pairs) x (8 batch groups of 32) x (8 i-chunks of 99)
// Block: 256 threads = 64 col-pairs x 4 row-groups; each thread: 8 batch rows.
// ---------------------------------------------------------------------------
__global__ __launch_bounds__(256) void mk_main(
    const float* __restrict__ x,  const float* __restrict__ wp,
    const float* __restrict__ wn, const float* __restrict__ bp,
    const float* __restrict__ bn, const float* __restrict__ npar,
    const unsigned int* __restrict__ maxbits, float* __restrict__ out)
{
    const int tx = threadIdx.x & 63;        // col-pair within tile
    const int ty = threadIdx.x >> 6;        // row group (0..3)
    const int jp = blockIdx.x * 64 + tx;    // output column 0..511
    const int b0 = blockIdx.y * 32;         // batch base of this block
    const int i0 = blockIdx.z * CHUNK;
    const int iN = min(NROWS - i0, CHUNK);

    // Stage {log2(2|x|), sign(x)} for this block's 32 batch rows x i-chunk.
    __shared__ float2 Ls[CHUNK * 32];
    for (int t = threadIdx.x; t < iN * 32; t += 256) {
        const int ii = t >> 5, bb = t & 31;
        const int i = i0 + ii;
        const float v = (i < NIN) ? x[(b0 + bb) * NIN + i] : 1.0f;
        const float s = (v > 0.0f) ? 1.0f : ((v < 0.0f) ? -1.0f : 0.0f);
        Ls[t] = make_float2(dlog2(2.0f * fabsf(v)), s);
    }
    __syncthreads();

    const float kG = G_DIFF_F / __uint_as_float(*maxbits);

    float acc[8];
    #pragma unroll
    for (int b = 0; b < 8; ++b) acc[b] = 0.0f;

    for (int ii = 0; ii < iN; ++ii) {
        const int i = i0 + ii;
        float wpv, wnv;
        if (i < NIN) { wpv = wp[i * NOUT + jp]; wnv = wn[i * NOUT + jp]; }
        else         { wpv = bp[jp];            wnv = bn[jp]; }
        const float2 nv = *(const float2*)(&npar[i * (2 * NOUT) + 2 * jp]);
        const float lgGp = dlog2(fmaf(kG, fmaxf(wpv, 0.0f), G_MIN_F));
        const float lgGn = dlog2(fmaf(kG, fmaxf(wnv, 0.0f), G_MIN_F));
        const float ep = dlog2(nv.x);
        const float en = dlog2(nv.y);
        const float2* lsrow = &Ls[ii * 32 + ty * 8];
        #pragma unroll
        for (int b = 0; b < 8; ++b) {
            const float2 ls = lsrow[b];               // broadcast (uniform per wave)
            const float tp = dexp2(fmaf(ep, ls.x, lgGp));
            const float tn = dexp2(fmaf(en, ls.x, lgGn));
            acc[b] = fmaf(ls.y, tp - tn, acc[b]);
        }
    }

    const float C = 0.5f / kG;   // V_REF / (k_V * k_G)
    #pragma unroll
    for (int b = 0; b < 8; ++b)
        unsafeAtomicAdd(&out[(b0 + ty * 8 + b) * NOUT + jp], C * acc[b]);
}

extern "C" void kernel_launch(void* const* d_in, const int* in_sizes, int n_in,
                              void* d_out, int out_size, void* d_ws, size_t ws_size,
                              hipStream_t stream) {
    const float* x    = (const float*)d_in[0];
    const float* wp   = (const float*)d_in[1];
    const float* wn   = (const float*)d_in[2];
    const float* bp   = (const float*)d_in[3];
    const float* bn   = (const float*)d_in[4];
    const float* npar = (const float*)d_in[5];
    float*        out = (float*)d_out;
    unsigned int* maxbits = (unsigned int*)d_ws;

    (void)hipMemsetAsync(d_out, 0, (size_t)BATCH * NOUT * sizeof(float), stream);
    (void)hipMemsetAsync(d_ws, 0, sizeof(unsigned int), stream);

    mk_max<<<64, 256, 0, stream>>>(wp, wn, bp, bn, maxbits);

    dim3 grid(8, 8, 8);
    mk_main<<<grid, 256, 0, stream>>>(x, wp, wn, bp, bn, npar, maxbits, out);
}

// Round 3
// 52.737 us; speedup vs baseline: 1.1427x; 1.1427x over previous
//
#include <hip/hip_runtime.h>

#define NIN   784
#define NOUT  512
#define NROWS 785      // NIN + 1 (bias row)
#define BATCH 256
#define CHUNK 25       // i-chunk per block; 32 chunks cover 785 (last has 10)
#define LSPAD 33       // 32 batches + 1 pad -> conflict-free transposed write

static constexpr float G_MIN_F  = (float)(1.0 / 983.3);
static constexpr float G_DIFF_F = (float)(1.0 / 281.3 - 1.0 / 983.3);

// device fast transcendental: v_log_f32 (log2), v_exp_f32 (2^x)
__device__ __forceinline__ float dlog2(float v) { return __builtin_amdgcn_logf(v); }
__device__ __forceinline__ float dexp2(float v) { return __builtin_amdgcn_exp2f(v); }

// ---------------------------------------------------------------------------
// Kernel 1: global max(|weights|) over w_pos, w_neg, b_pos, b_neg.
// ---------------------------------------------------------------------------
__global__ __launch_bounds__(256) void mk_max(
    const float* __restrict__ wp, const float* __restrict__ wn,
    const float* __restrict__ bp, const float* __restrict__ bn,
    unsigned int* __restrict__ out)
{
    float m = 0.0f;
    const int n = NIN * NOUT;
    for (int idx = blockIdx.x * 256 + threadIdx.x; idx < n; idx += gridDim.x * 256) {
        m = fmaxf(m, fabsf(wp[idx]));
        m = fmaxf(m, fabsf(wn[idx]));
    }
    if (blockIdx.x == 0 && threadIdx.x < NOUT) {
        m = fmaxf(m, fabsf(bp[threadIdx.x]));
        m = fmaxf(m, fabsf(bn[threadIdx.x]));
    }
    #pragma unroll
    for (int off = 1; off < 64; off <<= 1)
        m = fmaxf(m, __shfl_xor(m, off, 64));
    __shared__ float sm[4];
    if ((threadIdx.x & 63) == 0) sm[threadIdx.x >> 6] = m;
    __syncthreads();
    if (threadIdx.x == 0) {
        m = fmaxf(fmaxf(sm[0], sm[1]), fmaxf(sm[2], sm[3]));
        atomicMax(out, __float_as_uint(m));
    }
}

// ---------------------------------------------------------------------------
// Kernel 2: main memristor crossbar.
// y[b,j] = C * sum_i s[b,i] * ( 2^(ep*L + lgGp) - 2^(en*L + lgGn) )
// Grid: (8 col-tiles of 64) x (8 batch groups of 32) x (32 i-chunks of 25)
//   = 2048 blocks -> 8 blocks/CU -> 32 waves/CU (100% occupancy target).
// Block: 256 threads = 64 col-pairs (tx) x 4 batch row-groups (ty);
// each thread accumulates 8 batch rows in registers.
// ---------------------------------------------------------------------------
__global__ __launch_bounds__(256) void mk_main(
    const float* __restrict__ x,  const float* __restrict__ wp,
    const float* __restrict__ wn, const float* __restrict__ bp,
    const float* __restrict__ bn, const float* __restrict__ npar,
    const unsigned int* __restrict__ maxbits, float* __restrict__ out)
{
    const int tx = threadIdx.x & 63;        // col-pair within tile
    const int ty = threadIdx.x >> 6;        // batch row group (0..3)
    const int jp = blockIdx.x * 64 + tx;    // output column 0..511
    const int b0 = blockIdx.y * 32;         // batch base of this block
    const int i0 = blockIdx.z * CHUNK;
    const int iN = min(NROWS - i0, CHUNK);

    // Stage {log2(2|x|), sign(x)}: [ii][bb] with pad-33 stride.
    // Lanes vary ii fastest -> coalesced x reads; transposed LDS write is
    // 2-way bank aliased (free).
    __shared__ float2 Ls[CHUNK * LSPAD];
    for (int t = threadIdx.x; t < 32 * 32; t += 256) {
        const int bb = t >> 5, ii = t & 31;
        if (ii < iN) {
            const int i = i0 + ii;
            const float v = (i < NIN) ? x[(b0 + bb) * NIN + i] : 1.0f;
            const float s = (v > 0.0f) ? 1.0f : ((v < 0.0f) ? -1.0f : 0.0f);
            Ls[ii * LSPAD + bb] = make_float2(dlog2(2.0f * fabsf(v)), s);
        }
    }
    __syncthreads();

    const float kG = G_DIFF_F / __uint_as_float(*maxbits);

    float acc[8];
    #pragma unroll
    for (int b = 0; b < 8; ++b) acc[b] = 0.0f;

    for (int ii = 0; ii < iN; ++ii) {
        const int i = i0 + ii;
        float wpv, wnv;
        if (i < NIN) { wpv = wp[i * NOUT + jp]; wnv = wn[i * NOUT + jp]; }
        else         { wpv = bp[jp];            wnv = bn[jp]; }
        const float2 nv = *(const float2*)(&npar[i * (2 * NOUT) + 2 * jp]);
        const float lgGp = dlog2(fmaf(kG, fmaxf(wpv, 0.0f), G_MIN_F));
        const float lgGn = dlog2(fmaf(kG, fmaxf(wnv, 0.0f), G_MIN_F));
        const float ep = dlog2(nv.x);
        const float en = dlog2(nv.y);
        const float2* lsrow = &Ls[ii * LSPAD + ty * 8];
        #pragma unroll
        for (int b = 0; b < 8; ++b) {
            const float2 ls = lsrow[b];               // broadcast (uniform per wave)
            const float tp = dexp2(fmaf(ep, ls.x, lgGp));
            const float tn = dexp2(fmaf(en, ls.x, lgGn));
            acc[b] = fmaf(ls.y, tp - tn, acc[b]);
        }
    }

    const float C = 0.5f / kG;   // V_REF / (k_V * k_G)
    #pragma unroll
    for (int b = 0; b < 8; ++b)
        unsafeAtomicAdd(&out[(b0 + ty * 8 + b) * NOUT + jp], C * acc[b]);
}

extern "C" void kernel_launch(void* const* d_in, const int* in_sizes, int n_in,
                              void* d_out, int out_size, void* d_ws, size_t ws_size,
                              hipStream_t stream) {
    const float* x    = (const float*)d_in[0];
    const float* wp   = (const float*)d_in[1];
    const float* wn   = (const float*)d_in[2];
    const float* bp   = (const float*)d_in[3];
    const float* bn   = (const float*)d_in[4];
    const float* npar = (const float*)d_in[5];
    float*        out = (float*)d_out;
    unsigned int* maxbits = (unsigned int*)d_ws;

    (void)hipMemsetAsync(d_out, 0, (size_t)BATCH * NOUT * sizeof(float), stream);
    (void)hipMemsetAsync(d_ws, 0, sizeof(unsigned int), stream);

    mk_max<<<64, 256, 0, stream>>>(wp, wn, bp, bn, maxbits);

    dim3 grid(8, 8, 32);
    mk_main<<<grid, 256, 0, stream>>>(x, wp, wn, bp, bn, npar, maxbits, out);
}

// Round 4
// 49.514 us; speedup vs baseline: 1.2171x; 1.0651x over previous
//
#include <hip/hip_runtime.h>

#define NIN   784
#define NOUT  512
#define NROWS 785      // NIN + 1 (bias row)
#define BATCH 256
#define CHUNK 25       // i-chunk per block; 32 chunks cover 785 (last has 10)
#define LSPAD 33       // 32 batches + 1 pad

static constexpr float G_MIN_F  = (float)(1.0 / 983.3);
static constexpr float G_DIFF_F = (float)(1.0 / 281.3 - 1.0 / 983.3);

// device fast transcendental: v_log_f32 (log2), v_exp_f32 (2^x)
__device__ __forceinline__ float dlog2(float v) { return __builtin_amdgcn_logf(v); }
__device__ __forceinline__ float dexp2(float v) { return __builtin_amdgcn_exp2f(v); }

// ---------------------------------------------------------------------------
// Kernel 1: global max over w_pos, w_neg (vectorized) + biases.
// Values >= 0 after fabsf, so uint bit ordering == float ordering.
// ---------------------------------------------------------------------------
__global__ __launch_bounds__(256) void mk_max(
    const float* __restrict__ wp, const float* __restrict__ wn,
    const float* __restrict__ bp, const float* __restrict__ bn,
    unsigned int* __restrict__ out)
{
    float m = 0.0f;
    const int n4 = NIN * NOUT / 4;
    const float4* wp4 = (const float4*)wp;
    const float4* wn4 = (const float4*)wn;
    for (int idx = blockIdx.x * 256 + threadIdx.x; idx < n4; idx += gridDim.x * 256) {
        float4 a = wp4[idx], b = wn4[idx];
        m = fmaxf(m, fmaxf(fmaxf(fabsf(a.x), fabsf(a.y)), fmaxf(fabsf(a.z), fabsf(a.w))));
        m = fmaxf(m, fmaxf(fmaxf(fabsf(b.x), fabsf(b.y)), fmaxf(fabsf(b.z), fabsf(b.w))));
    }
    if (blockIdx.x == 0 && threadIdx.x < NOUT) {
        m = fmaxf(m, fabsf(bp[threadIdx.x]));
        m = fmaxf(m, fabsf(bn[threadIdx.x]));
    }
    #pragma unroll
    for (int off = 1; off < 64; off <<= 1)
        m = fmaxf(m, __shfl_xor(m, off, 64));
    __shared__ float sm[4];
    if ((threadIdx.x & 63) == 0) sm[threadIdx.x >> 6] = m;
    __syncthreads();
    if (threadIdx.x == 0) {
        m = fmaxf(fmaxf(sm[0], sm[1]), fmaxf(sm[2], sm[3]));
        atomicMax(out, __float_as_uint(m));
    }
}

// ---------------------------------------------------------------------------
// Kernel 1.5: per-(i,j) table {ep, lgGp, en, lgGn} -> float4 tab[i*NOUT+jp].
// Hoists 4 log2 + 2 clip-fma + 3 loads per (i,j) out of the main loop
// (was recomputed by all 8 batch-group blocks).
// ---------------------------------------------------------------------------
__global__ __launch_bounds__(256) void mk_table(
    const float* __restrict__ wp, const float* __restrict__ wn,
    const float* __restrict__ bp, const float* __restrict__ bn,
    const float* __restrict__ npar, const unsigned int* __restrict__ maxbits,
    float4* __restrict__ tab)
{
    const int t = blockIdx.x * 256 + threadIdx.x;
    if (t >= NROWS * NOUT) return;
    const int i = t >> 9, jp = t & 511;
    const float kG = G_DIFF_F / __uint_as_float(*maxbits);
    float wpv, wnv;
    if (i < NIN) { wpv = wp[i * NOUT + jp]; wnv = wn[i * NOUT + jp]; }
    else         { wpv = bp[jp];            wnv = bn[jp]; }
    const float2 nv = *(const float2*)(&npar[i * (2 * NOUT) + 2 * jp]);
    float4 r;
    r.x = dlog2(nv.x);                                    // ep
    r.y = dlog2(fmaf(kG, fmaxf(wpv, 0.0f), G_MIN_F));     // lgGp
    r.z = dlog2(nv.y);                                    // en
    r.w = dlog2(fmaf(kG, fmaxf(wnv, 0.0f), G_MIN_F));     // lgGn
    tab[t] = r;
}

// ---------------------------------------------------------------------------
// Kernel 2: main crossbar using the table.
// y[b,j] = C * sum_i s[b,i] * ( 2^(ep*L + lgGp) - 2^(en*L + lgGn) )
// Grid: (8 col-tiles of 64) x (8 batch groups of 32) x (32 i-chunks of 25).
// ---------------------------------------------------------------------------
__global__ __launch_bounds__(256) void mk_main(
    const float* __restrict__ x, const float4* __restrict__ tab,
    const unsigned int* __restrict__ maxbits, float* __restrict__ out)
{
    const int tx = threadIdx.x & 63;
    const int ty = threadIdx.x >> 6;
    const int jp = blockIdx.x * 64 + tx;
    const int b0 = blockIdx.y * 32;
    const int i0 = blockIdx.z * CHUNK;
    const int iN = min(NROWS - i0, CHUNK);

    __shared__ float2 Ls[CHUNK * LSPAD];
    for (int t = threadIdx.x; t < 32 * 32; t += 256) {
        const int bb = t >> 5, ii = t & 31;
        if (ii < iN) {
            const int i = i0 + ii;
            const float v = (i < NIN) ? x[(b0 + bb) * NIN + i] : 1.0f;
            const float s = (v > 0.0f) ? 1.0f : ((v < 0.0f) ? -1.0f : 0.0f);
            Ls[ii * LSPAD + bb] = make_float2(dlog2(2.0f * fabsf(v)), s);
        }
    }
    __syncthreads();

    float acc[8];
    #pragma unroll
    for (int b = 0; b < 8; ++b) acc[b] = 0.0f;

    const float4* trow = &tab[i0 * NOUT + jp];
    for (int ii = 0; ii < iN; ++ii) {
        const float4 tv = trow[ii * NOUT];        // {ep, lgGp, en, lgGn}
        const float2* lsrow = &Ls[ii * LSPAD + ty * 8];
        #pragma unroll
        for (int b = 0; b < 8; ++b) {
            const float2 ls = lsrow[b];           // wave-broadcast
            const float tp = dexp2(fmaf(tv.x, ls.x, tv.y));
            const float tn = dexp2(fmaf(tv.z, ls.x, tv.w));
            acc[b] = fmaf(ls.y, tp - tn, acc[b]);
        }
    }

    const float kG = G_DIFF_F / __uint_as_float(*maxbits);
    const float C = 0.5f / kG;
    #pragma unroll
    for (int b = 0; b < 8; ++b)
        unsafeAtomicAdd(&out[(b0 + ty * 8 + b) * NOUT + jp], C * acc[b]);
}

// ---------------------------------------------------------------------------
// Fallback main (round-3 path) if ws_size can't hold the table.
// ---------------------------------------------------------------------------
__global__ __launch_bounds__(256) void mk_main_fb(
    const float* __restrict__ x,  const float* __restrict__ wp,
    const float* __restrict__ wn, const float* __restrict__ bp,
    const float* __restrict__ bn, const float* __restrict__ npar,
    const unsigned int* __restrict__ maxbits, float* __restrict__ out)
{
    const int tx = threadIdx.x & 63;
    const int ty = threadIdx.x >> 6;
    const int jp = blockIdx.x * 64 + tx;
    const int b0 = blockIdx.y * 32;
    const int i0 = blockIdx.z * CHUNK;
    const int iN = min(NROWS - i0, CHUNK);

    __shared__ float2 Ls[CHUNK * LSPAD];
    for (int t = threadIdx.x; t < 32 * 32; t += 256) {
        const int bb = t >> 5, ii = t & 31;
        if (ii < iN) {
            const int i = i0 + ii;
            const float v = (i < NIN) ? x[(b0 + bb) * NIN + i] : 1.0f;
            const float s = (v > 0.0f) ? 1.0f : ((v < 0.0f) ? -1.0f : 0.0f);
            Ls[ii * LSPAD + bb] = make_float2(dlog2(2.0f * fabsf(v)), s);
        }
    }
    __syncthreads();

    const float kG = G_DIFF_F / __uint_as_float(*maxbits);
    float acc[8];
    #pragma unroll
    for (int b = 0; b < 8; ++b) acc[b] = 0.0f;

    for (int ii = 0; ii < iN; ++ii) {
        const int i = i0 + ii;
        float wpv, wnv;
        if (i < NIN) { wpv = wp[i * NOUT + jp]; wnv = wn[i * NOUT + jp]; }
        else         { wpv = bp[jp];            wnv = bn[jp]; }
        const float2 nv = *(const float2*)(&npar[i * (2 * NOUT) + 2 * jp]);
        const float lgGp = dlog2(fmaf(kG, fmaxf(wpv, 0.0f), G_MIN_F));
        const float lgGn = dlog2(fmaf(kG, fmaxf(wnv, 0.0f), G_MIN_F));
        const float ep = dlog2(nv.x);
        const float en = dlog2(nv.y);
        const float2* lsrow = &Ls[ii * LSPAD + ty * 8];
        #pragma unroll
        for (int b = 0; b < 8; ++b) {
            const float2 ls = lsrow[b];
            const float tp = dexp2(fmaf(ep, ls.x, lgGp));
            const float tn = dexp2(fmaf(en, ls.x, lgGn));
            acc[b] = fmaf(ls.y, tp - tn, acc[b]);
        }
    }

    const float C = 0.5f / kG;
    #pragma unroll
    for (int b = 0; b < 8; ++b)
        unsafeAtomicAdd(&out[(b0 + ty * 8 + b) * NOUT + jp], C * acc[b]);
}

extern "C" void kernel_launch(void* const* d_in, const int* in_sizes, int n_in,
                              void* d_out, int out_size, void* d_ws, size_t ws_size,
                              hipStream_t stream) {
    const float* x    = (const float*)d_in[0];
    const float* wp   = (const float*)d_in[1];
    const float* wn   = (const float*)d_in[2];
    const float* bp   = (const float*)d_in[3];
    const float* bn   = (const float*)d_in[4];
    const float* npar = (const float*)d_in[5];
    float*        out = (float*)d_out;
    unsigned int* maxbits = (unsigned int*)d_ws;

    (void)hipMemsetAsync(d_out, 0, (size_t)BATCH * NOUT * sizeof(float), stream);
    (void)hipMemsetAsync(d_ws, 0, sizeof(unsigned int), stream);

    mk_max<<<128, 256, 0, stream>>>(wp, wn, bp, bn, maxbits);

    const size_t tab_bytes = (size_t)NROWS * NOUT * sizeof(float4);
    dim3 grid(8, 8, 32);
    if (ws_size >= 256 + tab_bytes) {
        float4* tab = (float4*)((char*)d_ws + 256);
        mk_table<<<(NROWS * NOUT + 255) / 256, 256, 0, stream>>>(
            wp, wn, bp, bn, npar, maxbits, tab);
        mk_main<<<grid, 256, 0, stream>>>(x, tab, maxbits, out);
    } else {
        mk_main_fb<<<grid, 256, 0, stream>>>(x, wp, wn, bp, bn, npar, maxbits, out);
    }
}

// Round 5
// 43.364 us; speedup vs baseline: 1.3897x; 1.1418x over previous
//
#include <hip/hip_runtime.h>

#define NIN   784
#define NOUT  512
#define NROWS 785      // NIN + 1 (bias row)
#define BATCH 256
#define CHUNK 25       // i-chunk per block; 32 chunks cover 785 (last has 10)
#define LSPAD 33       // 32 batches + 1 pad

static constexpr float G_MIN_F  = (float)(1.0 / 983.3);
static constexpr float G_DIFF_F = (float)(1.0 / 281.3 - 1.0 / 983.3);

// device fast transcendental: v_log_f32 (log2), v_exp_f32 (2^x)
__device__ __forceinline__ float dlog2(float v) { return __builtin_amdgcn_logf(v); }
__device__ __forceinline__ float dexp2(float v) { return __builtin_amdgcn_exp2f(v); }

// ws layout: [0]=kG, [1]=C (floats); +256B: 128 partial maxima; +4096B: table
#define WS_PART_OFF 256
#define WS_TAB_OFF  4096

// ---------------------------------------------------------------------------
// Kernel 1: per-block partial max over |weights| (vectorized) + zero d_out.
// 128 blocks x 256 threads; partial[blk] always written -> no init needed.
// ---------------------------------------------------------------------------
__global__ __launch_bounds__(256) void mk_max(
    const float* __restrict__ wp, const float* __restrict__ wn,
    const float* __restrict__ bp, const float* __restrict__ bn,
    float* __restrict__ part, float4* __restrict__ out4)
{
    // zero d_out: 131072 floats = 32768 float4, one per thread
    const int gid = blockIdx.x * 256 + threadIdx.x;
    out4[gid] = make_float4(0.f, 0.f, 0.f, 0.f);

    float m = 0.0f;
    const int n4 = NIN * NOUT / 4;
    const float4* wp4 = (const float4*)wp;
    const float4* wn4 = (const float4*)wn;
    for (int idx = gid; idx < n4; idx += gridDim.x * 256) {
        float4 a = wp4[idx], b = wn4[idx];
        m = fmaxf(m, fmaxf(fmaxf(fabsf(a.x), fabsf(a.y)), fmaxf(fabsf(a.z), fabsf(a.w))));
        m = fmaxf(m, fmaxf(fmaxf(fabsf(b.x), fabsf(b.y)), fmaxf(fabsf(b.z), fabsf(b.w))));
    }
    if (blockIdx.x == 0 && threadIdx.x < NOUT) {
        m = fmaxf(m, fabsf(bp[threadIdx.x]));
        m = fmaxf(m, fabsf(bn[threadIdx.x]));
    }
    #pragma unroll
    for (int off = 1; off < 64; off <<= 1)
        m = fmaxf(m, __shfl_xor(m, off, 64));
    __shared__ float sm[4];
    if ((threadIdx.x & 63) == 0) sm[threadIdx.x >> 6] = m;
    __syncthreads();
    if (threadIdx.x == 0)
        part[blockIdx.x] = fmaxf(fmaxf(sm[0], sm[1]), fmaxf(sm[2], sm[3]));
}

// ---------------------------------------------------------------------------
// Kernel 1.25: reduce 128 partials -> kG, C. One block, 128 threads.
// ---------------------------------------------------------------------------
__global__ __launch_bounds__(128) void mk_kg(
    const float* __restrict__ part, float* __restrict__ kg)
{
    float m = part[threadIdx.x];
    #pragma unroll
    for (int off = 1; off < 64; off <<= 1)
        m = fmaxf(m, __shfl_xor(m, off, 64));
    __shared__ float sm[2];
    if ((threadIdx.x & 63) == 0) sm[threadIdx.x >> 6] = m;
    __syncthreads();
    if (threadIdx.x == 0) {
        m = fmaxf(sm[0], sm[1]);
        const float kG = G_DIFF_F / m;
        kg[0] = kG;
        kg[1] = 0.5f / kG;   // C = V_REF/(k_V*k_G)
    }
}

// ---------------------------------------------------------------------------
// Kernel 1.5: per-(i,j) table {ep, lgGp, en, lgGn}.
// ---------------------------------------------------------------------------
__global__ __launch_bounds__(256) void mk_table(
    const float* __restrict__ wp, const float* __restrict__ wn,
    const float* __restrict__ bp, const float* __restrict__ bn,
    const float* __restrict__ npar, const float* __restrict__ kg,
    float4* __restrict__ tab)
{
    const int t = blockIdx.x * 256 + threadIdx.x;
    if (t >= NROWS * NOUT) return;
    const int i = t >> 9, jp = t & 511;
    const float kG = kg[0];
    float wpv, wnv;
    if (i < NIN) { wpv = wp[i * NOUT + jp]; wnv = wn[i * NOUT + jp]; }
    else         { wpv = bp[jp];            wnv = bn[jp]; }
    const float2 nv = *(const float2*)(&npar[i * (2 * NOUT) + 2 * jp]);
    float4 r;
    r.x = dlog2(nv.x);                                    // ep
    r.y = dlog2(fmaf(kG, fmaxf(wpv, 0.0f), G_MIN_F));     // lgGp
    r.z = dlog2(nv.y);                                    // en
    r.w = dlog2(fmaf(kG, fmaxf(wnv, 0.0f), G_MIN_F));     // lgGn
    tab[t] = r;
}

// ---------------------------------------------------------------------------
// Kernel 2: main crossbar.
// y[b,j] = C * sum_i s[b,i] * ( 2^(ep*L + lgGp) - 2^(en*L + lgGn) )
// Grid (8,8,32); block 256 = 64 col-pairs x 4 batch groups; 8 batch rows/thread.
// ---------------------------------------------------------------------------
__global__ __launch_bounds__(256) void mk_main(
    const float* __restrict__ x, const float4* __restrict__ tab,
    const float* __restrict__ kg, float* __restrict__ out)
{
    const int tx = threadIdx.x & 63;
    const int ty = threadIdx.x >> 6;
    const int jp = blockIdx.x * 64 + tx;
    const int b0 = blockIdx.y * 32;
    const int i0 = blockIdx.z * CHUNK;
    const int iN = min(NROWS - i0, CHUNK);

    __shared__ float2 Ls[CHUNK * LSPAD];
    for (int t = threadIdx.x; t < 32 * 32; t += 256) {
        const int bb = t >> 5, ii = t & 31;
        if (ii < iN) {
            const int i = i0 + ii;
            const float v = (i < NIN) ? x[(b0 + bb) * NIN + i] : 1.0f;
            const float s = (v > 0.0f) ? 1.0f : ((v < 0.0f) ? -1.0f : 0.0f);
            Ls[ii * LSPAD + bb] = make_float2(dlog2(2.0f * fabsf(v)), s);
        }
    }
    __syncthreads();

    float acc[8];
    #pragma unroll
    for (int b = 0; b < 8; ++b) acc[b] = 0.0f;

    const float4* trow = &tab[i0 * NOUT + jp];

#define STEP(ii)                                                          \
    {                                                                     \
        const float4 tv = trow[(ii) * NOUT];                              \
        const float2* lsrow = &Ls[(ii) * LSPAD + ty * 8];                 \
        _Pragma("unroll")                                                 \
        for (int b = 0; b < 8; ++b) {                                     \
            const float2 ls = lsrow[b];                                   \
            const float tp = dexp2(fmaf(tv.x, ls.x, tv.y));               \
            const float tn = dexp2(fmaf(tv.z, ls.x, tv.w));               \
            acc[b] = fmaf(ls.y, tp - tn, acc[b]);                         \
        }                                                                 \
    }

    if (iN == CHUNK) {
        #pragma unroll 5
        for (int ii = 0; ii < CHUNK; ++ii) STEP(ii);
    } else {
        for (int ii = 0; ii < iN; ++ii) STEP(ii);
    }
#undef STEP

    const float C = kg[1];
    #pragma unroll
    for (int b = 0; b < 8; ++b)
        unsafeAtomicAdd(&out[(b0 + ty * 8 + b) * NOUT + jp], C * acc[b]);
}

// ---------------------------------------------------------------------------
// Fallback main (no table) if ws can't hold it.
// ---------------------------------------------------------------------------
__global__ __launch_bounds__(256) void mk_main_fb(
    const float* __restrict__ x,  const float* __restrict__ wp,
    const float* __restrict__ wn, const float* __restrict__ bp,
    const float* __restrict__ bn, const float* __restrict__ npar,
    const float* __restrict__ kg, float* __restrict__ out)
{
    const int tx = threadIdx.x & 63;
    const int ty = threadIdx.x >> 6;
    const int jp = blockIdx.x * 64 + tx;
    const int b0 = blockIdx.y * 32;
    const int i0 = blockIdx.z * CHUNK;
    const int iN = min(NROWS - i0, CHUNK);

    __shared__ float2 Ls[CHUNK * LSPAD];
    for (int t = threadIdx.x; t < 32 * 32; t += 256) {
        const int bb = t >> 5, ii = t & 31;
        if (ii < iN) {
            const int i = i0 + ii;
            const float v = (i < NIN) ? x[(b0 + bb) * NIN + i] : 1.0f;
            const float s = (v > 0.0f) ? 1.0f : ((v < 0.0f) ? -1.0f : 0.0f);
            Ls[ii * LSPAD + bb] = make_float2(dlog2(2.0f * fabsf(v)), s);
        }
    }
    __syncthreads();

    const float kG = kg[0];
    float acc[8];
    #pragma unroll
    for (int b = 0; b < 8; ++b) acc[b] = 0.0f;

    for (int ii = 0; ii < iN; ++ii) {
        const int i = i0 + ii;
        float wpv, wnv;
        if (i < NIN) { wpv = wp[i * NOUT + jp]; wnv = wn[i * NOUT + jp]; }
        else         { wpv = bp[jp];            wnv = bn[jp]; }
        const float2 nv = *(const float2*)(&npar[i * (2 * NOUT) + 2 * jp]);
        const float lgGp = dlog2(fmaf(kG, fmaxf(wpv, 0.0f), G_MIN_F));
        const float lgGn = dlog2(fmaf(kG, fmaxf(wnv, 0.0f), G_MIN_F));
        const float ep = dlog2(nv.x);
        const float en = dlog2(nv.y);
        const float2* lsrow = &Ls[ii * LSPAD + ty * 8];
        #pragma unroll
        for (int b = 0; b < 8; ++b) {
            const float2 ls = lsrow[b];
            const float tp = dexp2(fmaf(ep, ls.x, lgGp));
            const float tn = dexp2(fmaf(en, ls.x, lgGn));
            acc[b] = fmaf(ls.y, tp - tn, acc[b]);
        }
    }

    const float C = kg[1];
    #pragma unroll
    for (int b = 0; b < 8; ++b)
        unsafeAtomicAdd(&out[(b0 + ty * 8 + b) * NOUT + jp], C * acc[b]);
}

extern "C" void kernel_launch(void* const* d_in, const int* in_sizes, int n_in,
                              void* d_out, int out_size, void* d_ws, size_t ws_size,
                              hipStream_t stream) {
    const float* x    = (const float*)d_in[0];
    const float* wp   = (const float*)d_in[1];
    const float* wn   = (const float*)d_in[2];
    const float* bp   = (const float*)d_in[3];
    const float* bn   = (const float*)d_in[4];
    const float* npar = (const float*)d_in[5];
    float*        out = (float*)d_out;
    float*         kg = (float*)d_ws;
    float*       part = (float*)((char*)d_ws + WS_PART_OFF);

    // mk_max zeroes d_out (replaces fill dispatch) and writes 128 partial maxima
    mk_max<<<128, 256, 0, stream>>>(wp, wn, bp, bn, part, (float4*)out);
    mk_kg<<<1, 128, 0, stream>>>(part, kg);

    const size_t tab_bytes = (size_t)NROWS * NOUT * sizeof(float4);
    dim3 grid(8, 8, 32);
    if (ws_size >= WS_TAB_OFF + tab_bytes) {
        float4* tab = (float4*)((char*)d_ws + WS_TAB_OFF);
        mk_table<<<(NROWS * NOUT + 255) / 256, 256, 0, stream>>>(
            wp, wn, bp, bn, npar, kg, tab);
        mk_main<<<grid, 256, 0, stream>>>(x, tab, kg, out);
    } else {
        mk_main_fb<<<grid, 256, 0, stream>>>(x, wp, wn, bp, bn, npar, kg, out);
    }
}